// Round 9
// baseline (6590.858 us; speedup 1.0000x reference)
//
#include <hip/hip_runtime.h>
#include <math.h>

#define S 2048
#define MARGIN 0.7f
#define ITERS 500
#define NBLK 256    // cooperative grid: 1 block/CU on 256 CUs
#define TPB 512     // 8 waves/block, wave-per-row, 8 rows/block
#define NREP 8      // value replicas -> 32 pollers/word max

typedef unsigned long long u64;

// val layout (per kind): [2 slots][NREP][2048] u64 ; slot stride in elements
#define SLOT_STRIDE 16384

#define ALD(p) __hip_atomic_load((p), __ATOMIC_RELAXED, __HIP_MEMORY_SCOPE_AGENT)
#define AST(p, v) __hip_atomic_store((p), (v), __ATOMIC_RELAXED, __HIP_MEMORY_SCOPE_AGENT)

// ---------------------------------------------------------------------------
// init: log-marginals, zero accumulators, poison ALL tagged words (replay-safe)
// ---------------------------------------------------------------------------
__global__ __launch_bounds__(256) void init_marg_k(const float* __restrict__ qa,
                                                   const float* __restrict__ ta,
                                                   float* __restrict__ lmu,
                                                   float* __restrict__ lnu,
                                                   float* __restrict__ vt,
                                                   float* __restrict__ dist2,
                                                   u64* __restrict__ valU,
                                                   u64* __restrict__ valV) {
  int i = blockIdx.x * 256 + threadIdx.x;   // 0..2047
  lmu[i] = __logf(qa[i]);
  lnu[i] = __logf(ta[i]);
  vt[i] = 0.f;     // will accumulate y2 (vt init = v0 + y2 = y2 since v0 = 0)
  dist2[i] = 0.f;
  const u64 poison = 0xFFFFFFFF00000000ull;  // hi never equals any ph (0..1000)
#pragma unroll
  for (int k = 0; k < 16; ++k) {             // 2 slots x 8 reps per kind
    valU[i + (k << 11)] = poison;
    valV[i + (k << 11)] = poison;
  }
}

// vt[j] += sum_d TF[d,j]^2   (8 j-blocks x 8 d-chunks, atomic combine)
__global__ __launch_bounds__(256) void colsumsq_k(const float* __restrict__ TF,
                                                  float* __restrict__ vt) {
  int jb = blockIdx.x & 7, dc = blockIdx.x >> 3;
  int j = jb * 256 + threadIdx.x;
  int d0 = dc * 256;
  float acc = 0.f;
  for (int d = d0; d < d0 + 256; ++d) {
    float v = TF[d * S + j];
    acc = fmaf(v, v, acc);
  }
  atomicAdd(&vt[j], acc);
}

// valV slot0 <- pack(v0=y2, tag 0) in all NREP replicas
__global__ __launch_bounds__(256) void pack_v0_k(const float* __restrict__ vt,
                                                 u64* __restrict__ valV) {
  int i = blockIdx.x * 256 + threadIdx.x;
  u64 w = (u64)__float_as_uint(vt[i]);       // tag 0 in high word
#pragma unroll
  for (int r = 0; r < NREP; ++r) valV[(r << 11) + i] = w;
}

// ---------------------------------------------------------------------------
// C[i,j] = alpha * sum_k A[k*S+i] * B[k*S+j]   (128x128 tile, BK=16, 8x8/thread)
// ---------------------------------------------------------------------------
__global__ __launch_bounds__(256) void gemm_tn_k(const float* __restrict__ A,
                                                 const float* __restrict__ B,
                                                 float* __restrict__ C, float alpha) {
  __shared__ float As[16][128];
  __shared__ float Bs[16][128];
  int t = threadIdx.x;
  int i0 = blockIdx.y * 128, j0 = blockIdx.x * 128;
  int tx = t & 15, ty = t >> 4;
  float acc[8][8];
#pragma unroll
  for (int r = 0; r < 8; ++r)
#pragma unroll
    for (int c = 0; c < 8; ++c) acc[r][c] = 0.f;

  int e = t * 4;
  int dd0 = e >> 7, ii = e & 127;
  int dd1 = dd0 + 8;
  for (int k0 = 0; k0 < S; k0 += 16) {
    float4 a0 = *(const float4*)&A[(k0 + dd0) * S + i0 + ii];
    float4 b0 = *(const float4*)&B[(k0 + dd0) * S + j0 + ii];
    float4 a1 = *(const float4*)&A[(k0 + dd1) * S + i0 + ii];
    float4 b1 = *(const float4*)&B[(k0 + dd1) * S + j0 + ii];
    __syncthreads();
    *(float4*)&As[dd0][ii] = a0; *(float4*)&Bs[dd0][ii] = b0;
    *(float4*)&As[dd1][ii] = a1; *(float4*)&Bs[dd1][ii] = b1;
    __syncthreads();
#pragma unroll
    for (int kk = 0; kk < 16; ++kk) {
      float a[8], b[8];
      *(float4*)&a[0] = *(const float4*)&As[kk][ty * 8];
      *(float4*)&a[4] = *(const float4*)&As[kk][ty * 8 + 4];
      *(float4*)&b[0] = *(const float4*)&Bs[kk][tx * 4];
      *(float4*)&b[4] = *(const float4*)&Bs[kk][64 + tx * 4];
#pragma unroll
      for (int r = 0; r < 8; ++r)
#pragma unroll
        for (int c = 0; c < 8; ++c) acc[r][c] = fmaf(a[r], b[c], acc[r][c]);
    }
  }
#pragma unroll
  for (int r = 0; r < 8; ++r) {
    int i = i0 + ty * 8 + r;
    float4 o0 = make_float4(acc[r][0] * alpha, acc[r][1] * alpha, acc[r][2] * alpha, acc[r][3] * alpha);
    float4 o1 = make_float4(acc[r][4] * alpha, acc[r][5] * alpha, acc[r][6] * alpha, acc[r][7] * alpha);
    *(float4*)&C[i * S + j0 + tx * 4] = o0;
    *(float4*)&C[i * S + j0 + 64 + tx * 4] = o1;
  }
}

// ---------------------------------------------------------------------------
// out[j*S+i] = in[i*S+j]  (64x64 LDS tiles)
// ---------------------------------------------------------------------------
__global__ __launch_bounds__(256) void transpose_k(const float* __restrict__ in,
                                                   float* __restrict__ out) {
  __shared__ float tile[64][65];
  int i0 = blockIdx.y * 64, j0 = blockIdx.x * 64;
  int tx = threadIdx.x & 63, ty = threadIdx.x >> 6;  // ty 0..3
#pragma unroll
  for (int r = 0; r < 16; ++r) {
    int row = r * 4 + ty;
    tile[row][tx] = in[(i0 + row) * S + j0 + tx];
  }
  __syncthreads();
#pragma unroll
  for (int r = 0; r < 16; ++r) {
    int row = r * 4 + ty;
    out[(j0 + row) * S + i0 + tx] = tile[tx][row];
  }
}

// ---------------------------------------------------------------------------
// Persistent cooperative Sinkhorn — LDS-resident G + BARRIER-FREE per-wave
// pipelined dataflow (v3 of the dataflow family; R6 was the best at 3.96us/ph).
//
// Per phase (tag ph, strictly increasing 0,1,2,...):
//   wave w: poll 32 sentinels of its own pot-chunk w (replica bid&7) ->
//           read 2KB chunk (tag-verified) -> deposit into s_pot[ph&1] ->
//           s_ready[w]=ph (LDS release) ->
//           for g=0..7: acquire-spin s_ready[g]==ph, add G-row chunk (LDS),
//           retain p_g, fmax-accumulate row max ->
//           butterfly max -> sum EXACTLY in the verified p0..p7 order ->
//           lanes 0..7 publish own row to 8 replicas.
// NO __syncthreads in the loop: s_pot is phase-parity double-buffered (2
// phases deep) and WAR follows inductively from the dataflow (publish(p) =>
// consumed(p-1) => all LDS flags p-1 => all deposits p-1 => ALL blocks
// published p-1 => every wave consumed p-2). LDS tags are monotonic with no
// skips, so no spinner can be passed over. Tags poisoned in init (replay-
// safe). fmax is exact/associative and the exp-sum order is unchanged ->
// LSE is bit-identical to rounds 0/3/5/6/7 (absmax 0.0).
// ---------------------------------------------------------------------------
#define PMAX(P) fmaxf(fmaxf(P.x, P.y), fmaxf(P.z, P.w))
#define PEXPS(P) (__expf(P.x - m) + __expf(P.y - m) + __expf(P.z - m) + __expf(P.w - m))

#define CHUNK(g, P)                                                            \
  while (__hip_atomic_load(&s_ready[g], __ATOMIC_ACQUIRE,                      \
                           __HIP_MEMORY_SCOPE_WORKGROUP) != ph) {}             \
  {                                                                            \
    float4 _q = *(const float4*)&s_pot[pb + ((g) << 8) + (lane << 2)];         \
    float4 _a = *(const float4*)&grow[((g) << 8) + (lane << 2)];               \
    P = make_float4(_q.x + _a.x, _q.y + _a.y, _q.z + _a.z, _q.w + _a.w);       \
    mx = fmaxf(mx, PMAX(P));                                                   \
  }

__device__ __forceinline__ float pass_lse(const u64* __restrict__ base,
                                          unsigned ph,
                                          const float* __restrict__ grow,
                                          float* __restrict__ s_pot,
                                          unsigned* __restrict__ s_ready,
                                          int wv, int lane, float lmarg) {
  // 1. poll own-chunk sentinels: 32 producer lines, words 0 and 4
  {
    const int b = (wv << 5) + (lane & 31);           // producer block id
    const int idx = (b << 3) + ((lane >> 5) << 2);   // its word 0 or 4
    bool ok = false;
    do {
      if (!ok) ok = ((unsigned)(ALD(&base[idx]) >> 32) == ph);
    } while (!__all(ok));
  }
  // 2. read own chunk: 4 words/lane, tag-verified (covers partial-line vis.)
  const int e = (wv << 8) + (lane << 2);
  u64 w0 = ALD(&base[e + 0]);
  u64 w1 = ALD(&base[e + 1]);
  u64 w2 = ALD(&base[e + 2]);
  u64 w3 = ALD(&base[e + 3]);
  unsigned ok4 = 0;
  do {
    if (!(ok4 & 1u)) { if ((unsigned)(w0 >> 32) == ph) ok4 |= 1u; else w0 = ALD(&base[e + 0]); }
    if (!(ok4 & 2u)) { if ((unsigned)(w1 >> 32) == ph) ok4 |= 2u; else w1 = ALD(&base[e + 1]); }
    if (!(ok4 & 4u)) { if ((unsigned)(w2 >> 32) == ph) ok4 |= 4u; else w2 = ALD(&base[e + 2]); }
    if (!(ok4 & 8u)) { if ((unsigned)(w3 >> 32) == ph) ok4 |= 8u; else w3 = ALD(&base[e + 3]); }
  } while (ok4 != 0xFu);
  // 3. deposit into parity buffer + release flag (no block barrier!)
  const int pb = (int)(ph & 1u) << 11;
  *(float4*)&s_pot[pb + e] = make_float4(__uint_as_float((unsigned)w0),
                                         __uint_as_float((unsigned)w1),
                                         __uint_as_float((unsigned)w2),
                                         __uint_as_float((unsigned)w3));
  __hip_atomic_store(&s_ready[wv], ph, __ATOMIC_RELEASE,
                     __HIP_MEMORY_SCOPE_WORKGROUP);
  // 4. pipelined gather: consume chunks as they land; retain p0..p7
  float4 p0, p1, p2, p3, p4, p5, p6, p7;
  float mx = -3.402823466e38f;
  CHUNK(0, p0) CHUNK(1, p1) CHUNK(2, p2) CHUNK(3, p3)
  CHUNK(4, p4) CHUNK(5, p5) CHUNK(6, p6) CHUNK(7, p7)
  // 5. exact row max (fmax assoc/comm: same value as verified tree)
#pragma unroll
  for (int off = 32; off; off >>= 1) mx = fmaxf(mx, __shfl_xor(mx, off));
  const float m = mx;
  // 6. sum in the EXACT verified order -> bit-identical
  float s = PEXPS(p0) + PEXPS(p1) + PEXPS(p2) + PEXPS(p3) +
            PEXPS(p4) + PEXPS(p5) + PEXPS(p6) + PEXPS(p7);
#pragma unroll
  for (int off = 32; off; off >>= 1) s += __shfl_xor(s, off);
  return lmarg - (m + __logf(s));
}

__global__ __launch_bounds__(TPB) void sinkhorn_k(
    const float* __restrict__ Gp, const float* __restrict__ GpT,
    const float* __restrict__ lmu, const float* __restrict__ lnu,
    float* __restrict__ ut, float* __restrict__ vt,
    u64* __restrict__ valU, u64* __restrict__ valV) {
  __shared__ float s_gu[8 * S];    // 64KB: this block's 8 Gp rows
  __shared__ float s_gv[8 * S];    // 64KB: this block's 8 GpT rows
  __shared__ float s_pot[2 * S];   // 16KB: phase-parity staged potential
  __shared__ unsigned s_ready[8];  // per-chunk monotonic LDS tags

  const int t = threadIdx.x;
  const int wv = t >> 6, lane = t & 63;
  const int bid = (int)blockIdx.x;
  const int row = (bid << 3) + wv;
  const int rep = bid & (NREP - 1);

  // one-time stage of this block's G rows into LDS
  {
    const float* gu = Gp + (size_t)row * S;
    const float* gv = GpT + (size_t)row * S;
    float* lgu = s_gu + wv * S;
    float* lgv = s_gv + wv * S;
#pragma unroll
    for (int c = 0; c < 8; ++c) {
      int j = (lane << 2) + (c << 8);
      *(float4*)&lgu[j] = *(const float4*)&gu[j];
      *(float4*)&lgv[j] = *(const float4*)&gv[j];
    }
  }
  if (t < 8) s_ready[t] = 0xFFFFFFFFu;   // != any real tag
  const float lmu_r = lmu[row];
  const float lnu_r = lnu[row];
  const float* grow_u = s_gu + wv * S;
  const float* grow_v = s_gv + wv * S;
  float uLast = 0.f, vLast = 0.f;
  __syncthreads();   // G staged + flags init (the only barrier)

  for (int it = 0; it < ITERS; ++it) {
    const size_t so = (size_t)(it & 1) * SLOT_STRIDE;
    const size_t so2 = (size_t)((it + 1) & 1) * SLOT_STRIDE;
    const unsigned phv = 2u * (unsigned)it;   // tag of v_it
    const unsigned phu = phv + 1u;            // tag of u_it

    // ---- u-pass: u_t = lmu - LSE(Gp + v_t) ----
    float nu = pass_lse(valV + so + ((size_t)rep << 11), phv, grow_u,
                        s_pot, s_ready, wv, lane, lmu_r);
    uLast = nu;
    if (lane < 8)   // publish own row to 8 replicas (no LDS, no barrier)
      AST(&valU[so + ((size_t)lane << 11) + row],
          ((u64)phu << 32) | (u64)__float_as_uint(nu));

    // ---- v-pass: v_{t+1} = lnu - LSE(GpT + u_t) ----
    float nv = pass_lse(valU + so + ((size_t)rep << 11), phu, grow_v,
                        s_pot, s_ready, wv, lane, lnu_r);
    vLast = nv;
    if (lane < 8)
      AST(&valV[so2 + ((size_t)lane << 11) + row],
          ((u64)(phv + 2u) << 32) | (u64)__float_as_uint(nv));
  }
  // final potentials -> plain arrays for the epilogue kernels
  if (lane == 0) {
    ut[row] = uLast;
    vt[row] = vLast;
  }
}

// ---------------------------------------------------------------------------
// RT[d,i] = sum_j TF[d,j] * exp( GpT[j*S+i] + ut[i] + vt[j] )
// ---------------------------------------------------------------------------
__global__ __launch_bounds__(256) void rt_gemm_k(const float* __restrict__ TF,
                                                 const float* __restrict__ GpT,
                                                 const float* __restrict__ ut,
                                                 const float* __restrict__ vt,
                                                 float* __restrict__ RT) {
  __shared__ float As[16][128];
  __shared__ float Bs[16][128];
  int t = threadIdx.x;
  int d0 = blockIdx.y * 128, i0 = blockIdx.x * 128;
  int tx = t & 15, ty = t >> 4;
  float acc[8][8];
#pragma unroll
  for (int r = 0; r < 8; ++r)
#pragma unroll
    for (int c = 0; c < 8; ++c) acc[r][c] = 0.f;

  int akk = (t * 4) & 15, add0 = t >> 2;
  int eb = t * 4;
  int bkk0 = eb >> 7, bii = eb & 127, bkk1 = bkk0 + 8;
  float4 u4 = *(const float4*)&ut[i0 + bii];

  for (int k0 = 0; k0 < S; k0 += 16) {
    float4 av0 = *(const float4*)&TF[(d0 + add0) * S + k0 + akk];
    float4 av1 = *(const float4*)&TF[(d0 + add0 + 64) * S + k0 + akk];
    float4 g0 = *(const float4*)&GpT[(k0 + bkk0) * S + i0 + bii];
    float4 g1 = *(const float4*)&GpT[(k0 + bkk1) * S + i0 + bii];
    float v0 = vt[k0 + bkk0], v1 = vt[k0 + bkk1];
    __syncthreads();
    As[akk + 0][add0] = av0.x; As[akk + 1][add0] = av0.y;
    As[akk + 2][add0] = av0.z; As[akk + 3][add0] = av0.w;
    As[akk + 0][add0 + 64] = av1.x; As[akk + 1][add0 + 64] = av1.y;
    As[akk + 2][add0 + 64] = av1.z; As[akk + 3][add0 + 64] = av1.w;
    float4 p0 = make_float4(__expf(g0.x + u4.x + v0), __expf(g0.y + u4.y + v0),
                            __expf(g0.z + u4.z + v0), __expf(g0.w + u4.w + v0));
    float4 p1 = make_float4(__expf(g1.x + u4.x + v1), __expf(g1.y + u4.y + v1),
                            __expf(g1.z + u4.z + v1), __expf(g1.w + u4.w + v1));
    *(float4*)&Bs[bkk0][bii] = p0;
    *(float4*)&Bs[bkk1][bii] = p1;
    __syncthreads();
#pragma unroll
    for (int kk = 0; kk < 16; ++kk) {
      float a[8], b[8];
      *(float4*)&a[0] = *(const float4*)&As[kk][ty * 8];
      *(float4*)&a[4] = *(const float4*)&As[kk][ty * 8 + 4];
      *(float4*)&b[0] = *(const float4*)&Bs[kk][tx * 4];
      *(float4*)&b[4] = *(const float4*)&Bs[kk][64 + tx * 4];
#pragma unroll
      for (int r = 0; r < 8; ++r)
#pragma unroll
        for (int c = 0; c < 8; ++c) acc[r][c] = fmaf(a[r], b[c], acc[r][c]);
    }
  }
#pragma unroll
  for (int r = 0; r < 8; ++r) {
    int d = d0 + ty * 8 + r;
    *(float4*)&RT[d * S + i0 + tx * 4] = *(float4*)&acc[r][0];
    *(float4*)&RT[d * S + i0 + 64 + tx * 4] = *(float4*)&acc[r][4];
  }
}

// dist2[i] += sum_{d in chunk} (qa[i]*QF[d,i] - RT[d,i])^2
__global__ __launch_bounds__(256) void dist2_partial_k(const float* __restrict__ QF,
                                                       const float* __restrict__ RT,
                                                       const float* __restrict__ qa,
                                                       float* __restrict__ dist2) {
  int ib = blockIdx.x & 7, dc = blockIdx.x >> 3;
  int i = ib * 256 + threadIdx.x;
  float qai = qa[i];
  float acc = 0.f;
  int d0 = dc * 256;
  for (int d = d0; d < d0 + 256; ++d) {
    float q = QF[d * S + i];
    float r = RT[d * S + i];
    float x = fmaf(qai, q, -r);
    acc = fmaf(x, x, acc);
  }
  atomicAdd(&dist2[i], acc);
}

__global__ __launch_bounds__(256) void loss_final_k(const float* __restrict__ dist2,
                                                    const float* __restrict__ label,
                                                    float* __restrict__ out) {
  int t = threadIdx.x;
  float acc = 0.f;
#pragma unroll
  for (int k = 0; k < 8; ++k) {
    int i = t + k * 256;
    float d2 = dist2[i];
    float dist = sqrtf(d2);
    float lab = label[i];
    float neg = fmaxf(MARGIN - dist, 0.f);
    acc += 0.5f * lab * d2 + 0.5f * (1.f - lab) * neg * neg;
  }
#pragma unroll
  for (int off = 32; off; off >>= 1) acc += __shfl_xor(acc, off);
  __shared__ float wsum[4];
  int wave = t >> 6, lane = t & 63;
  if (lane == 0) wsum[wave] = acc;
  __syncthreads();
  if (t == 0) out[0] = wsum[0] + wsum[1] + wsum[2] + wsum[3];
}

// ---------------------------------------------------------------------------
extern "C" void kernel_launch(void* const* d_in, const int* in_sizes, int n_in,
                              void* d_out, int out_size, void* d_ws, size_t ws_size,
                              hipStream_t stream) {
  const float* QF  = (const float*)d_in[0];  // [D, m] d-major
  const float* qa  = (const float*)d_in[1];  // [m]
  const float* TF  = (const float*)d_in[2];  // [D, n] d-major
  const float* ta  = (const float*)d_in[3];  // [n]
  const float* lab = (const float*)d_in[4];  // [m]
  float* out = (float*)d_out;

  float* ws = (float*)d_ws;
  float* Gp    = ws;                  // S*S : G' = -2 X^T Y  (reused as RT later)
  float* GpT   = Gp + S * S;          // S*S : G'^T
  float* ut    = GpT + S * S;         // S
  float* vt    = ut + S;              // S
  float* lmu   = vt + S;              // S
  float* lnu   = lmu + S;             // S
  float* dist2 = lnu + S;             // S
  u64* valU = (u64*)(dist2 + S);      // [2][NREP][2048] u64 (256KB)
  u64* valV = valU + 2 * SLOT_STRIDE; // [2][NREP][2048] u64 (256KB)
  // total: 2*S*S + 5*S floats + 512KB sync state ~= 34.1 MB

  init_marg_k<<<8, 256, 0, stream>>>(qa, ta, lmu, lnu, vt, dist2, valU, valV);
  colsumsq_k<<<64, 256, 0, stream>>>(TF, vt);   // vt = y2 (== v0 + y2)
  pack_v0_k<<<8, 256, 0, stream>>>(vt, valV);
  gemm_tn_k<<<dim3(16, 16), 256, 0, stream>>>(QF, TF, Gp, -2.0f);
  transpose_k<<<dim3(32, 32), 256, 0, stream>>>(Gp, GpT);

  // whole Sinkhorn loop in one persistent cooperative kernel (static 144KB LDS)
  {
    const float* cGp = Gp; const float* cGpT = GpT;
    const float* clmu = lmu; const float* clnu = lnu;
    float* cut = ut; float* cvt = vt;
    u64* cvalU = valU; u64* cvalV = valV;
    void* kargs[] = {&cGp, &cGpT, &clmu, &clnu, &cut, &cvt, &cvalU, &cvalV};
    hipLaunchCooperativeKernel((const void*)sinkhorn_k, dim3(NBLK), dim3(TPB),
                               kargs, 0, stream);
  }

  // RT = P @ tf computed transposed: RT[d,i]; aliases Gp (G' dead after loop)
  rt_gemm_k<<<dim3(16, 16), 256, 0, stream>>>(TF, GpT, ut, vt, Gp);
  dist2_partial_k<<<64, 256, 0, stream>>>(QF, Gp, qa, dist2);
  loss_final_k<<<1, 256, 0, stream>>>(dist2, lab, out);
}

// Round 10
// 4414.380 us; speedup vs baseline: 1.4930x; 1.4930x over previous
//
#include <hip/hip_runtime.h>
#include <math.h>

#define S 2048
#define MARGIN 0.7f
#define ITERS 500

// ---------------------------------------------------------------------------
// init: log-marginals, zero accumulators
// ---------------------------------------------------------------------------
__global__ __launch_bounds__(256) void init_marg_k(const float* __restrict__ qa,
                                                   const float* __restrict__ ta,
                                                   float* __restrict__ lmu,
                                                   float* __restrict__ lnu,
                                                   float* __restrict__ vt,
                                                   float* __restrict__ dist2) {
  int i = blockIdx.x * 256 + threadIdx.x;
  lmu[i] = __logf(qa[i]);
  lnu[i] = __logf(ta[i]);
  vt[i] = 0.f;     // will accumulate y2 (vt init = v0 + y2 = y2 since v0 = 0)
  dist2[i] = 0.f;
}

// vt[j] += sum_d TF[d,j]^2   (8 j-blocks x 8 d-chunks, atomic combine)
__global__ __launch_bounds__(256) void colsumsq_k(const float* __restrict__ TF,
                                                  float* __restrict__ vt) {
  int jb = blockIdx.x & 7, dc = blockIdx.x >> 3;
  int j = jb * 256 + threadIdx.x;
  int d0 = dc * 256;
  float acc = 0.f;
  for (int d = d0; d < d0 + 256; ++d) {
    float v = TF[d * S + j];
    acc = fmaf(v, v, acc);
  }
  atomicAdd(&vt[j], acc);
}

// ---------------------------------------------------------------------------
// C[i,j] = alpha * sum_k A[k*S+i] * B[k*S+j]   (128x128 tile, BK=16)
// 512 threads (8 waves/CU vs the old 256-thread 4 waves/CU = 1 wave/SIMD,
// which had zero cross-wave latency hiding). Each thread: 8 rows x 4 cols.
// Per-element k-accumulation order identical to the 256-thread version ->
// bit-identical C.
// ---------------------------------------------------------------------------
__global__ __launch_bounds__(512) void gemm_tn_k(const float* __restrict__ A,
                                                 const float* __restrict__ B,
                                                 float* __restrict__ C, float alpha) {
  __shared__ float As[16][128];
  __shared__ float Bs[16][128];
  int t = threadIdx.x;
  int i0 = blockIdx.y * 128, j0 = blockIdx.x * 128;
  int tx = t & 31, ty = t >> 5;   // tx: 32 col-groups of 4, ty: 16 row-groups of 8
  float acc[8][4];
#pragma unroll
  for (int r = 0; r < 8; ++r)
#pragma unroll
    for (int c = 0; c < 4; ++c) acc[r][c] = 0.f;

  int e = t * 4;
  int dd = e >> 7, ii = e & 127;   // dd 0..15, ii 0..124
  for (int k0 = 0; k0 < S; k0 += 16) {
    float4 a0 = *(const float4*)&A[(k0 + dd) * S + i0 + ii];
    float4 b0 = *(const float4*)&B[(k0 + dd) * S + j0 + ii];
    __syncthreads();
    *(float4*)&As[dd][ii] = a0;
    *(float4*)&Bs[dd][ii] = b0;
    __syncthreads();
#pragma unroll
    for (int kk = 0; kk < 16; ++kk) {
      float a[8], b[4];
      *(float4*)&a[0] = *(const float4*)&As[kk][ty * 8];
      *(float4*)&a[4] = *(const float4*)&As[kk][ty * 8 + 4];
      *(float4*)&b[0] = *(const float4*)&Bs[kk][tx * 4];
#pragma unroll
      for (int r = 0; r < 8; ++r)
#pragma unroll
        for (int c = 0; c < 4; ++c) acc[r][c] = fmaf(a[r], b[c], acc[r][c]);
    }
  }
#pragma unroll
  for (int r = 0; r < 8; ++r) {
    int i = i0 + ty * 8 + r;
    float4 o = make_float4(acc[r][0] * alpha, acc[r][1] * alpha,
                           acc[r][2] * alpha, acc[r][3] * alpha);
    *(float4*)&C[i * S + j0 + tx * 4] = o;
  }
}

// ---------------------------------------------------------------------------
// out[j*S+i] = in[i*S+j]  (64x64 LDS tiles)
// ---------------------------------------------------------------------------
__global__ __launch_bounds__(256) void transpose_k(const float* __restrict__ in,
                                                   float* __restrict__ out) {
  __shared__ float tile[64][65];
  int i0 = blockIdx.y * 64, j0 = blockIdx.x * 64;
  int tx = threadIdx.x & 63, ty = threadIdx.x >> 6;  // ty 0..3
#pragma unroll
  for (int r = 0; r < 16; ++r) {
    int row = r * 4 + ty;
    tile[row][tx] = in[(i0 + row) * S + j0 + tx];
  }
  __syncthreads();
#pragma unroll
  for (int r = 0; r < 16; ++r) {
    int row = r * 4 + ty;
    out[(j0 + row) * S + i0 + tx] = tile[tx][row];
  }
}

// ---------------------------------------------------------------------------
// lse8_k: 4 rows per block, wave-per-row, pot staged once in LDS.
// Best measured loop structure (R8): graph-serialized launches pipeline
// ramp/drain across dependent dispatches (~3.7us/pass effective) — beats all
// six persistent-kernel sync mechanisms tried in R3-R7/R9 (3.96-6.8us/ph).
// ---------------------------------------------------------------------------
#define PADD(P, A) P.x += A.x; P.y += A.y; P.z += A.z; P.w += A.w
#define PMAX(P) fmaxf(fmaxf(P.x, P.y), fmaxf(P.z, P.w))
#define PEXPS(P) (__expf(P.x - m) + __expf(P.y - m) + __expf(P.z - m) + __expf(P.w - m))

__global__ __launch_bounds__(256) void lse8_k(const float* __restrict__ G,
                                              const float* __restrict__ inPot,
                                              const float* __restrict__ logMarg,
                                              float* __restrict__ outPot) {
  __shared__ float s_pot[S];
  const int t = threadIdx.x;
  const int wv = t >> 6, lane = t & 63;
  const int row = (int)blockIdx.x * 4 + wv;

  // stage pot: 256 threads x 8 floats = 8KB, coalesced, conflict-free
  {
    int e = t << 3;
    *(float4*)&s_pot[e] = *(const float4*)&inPot[e];
    *(float4*)&s_pot[e + 4] = *(const float4*)&inPot[e + 4];
  }
  __syncthreads();

  const float* g = G + (size_t)row * S;
  const int j0 = lane << 2;
  float4 p0 = *(const float4*)&s_pot[j0];
  float4 p1 = *(const float4*)&s_pot[j0 + 256];
  float4 p2 = *(const float4*)&s_pot[j0 + 512];
  float4 p3 = *(const float4*)&s_pot[j0 + 768];
  float4 p4 = *(const float4*)&s_pot[j0 + 1024];
  float4 p5 = *(const float4*)&s_pot[j0 + 1280];
  float4 p6 = *(const float4*)&s_pot[j0 + 1536];
  float4 p7 = *(const float4*)&s_pot[j0 + 1792];
  float4 a0 = *(const float4*)&g[j0];
  float4 a1 = *(const float4*)&g[j0 + 256];
  float4 a2 = *(const float4*)&g[j0 + 512];
  float4 a3 = *(const float4*)&g[j0 + 768];
  float4 a4 = *(const float4*)&g[j0 + 1024];
  float4 a5 = *(const float4*)&g[j0 + 1280];
  float4 a6 = *(const float4*)&g[j0 + 1536];
  float4 a7 = *(const float4*)&g[j0 + 1792];
  PADD(p0, a0); PADD(p1, a1); PADD(p2, a2); PADD(p3, a3);
  PADD(p4, a4); PADD(p5, a5); PADD(p6, a6); PADD(p7, a7);
  float m0 = PMAX(p0), m1 = PMAX(p1), m2 = PMAX(p2), m3 = PMAX(p3);
  float m4 = PMAX(p4), m5 = PMAX(p5), m6 = PMAX(p6), m7 = PMAX(p7);
  m0 = fmaxf(m0, m1); m2 = fmaxf(m2, m3); m4 = fmaxf(m4, m5); m6 = fmaxf(m6, m7);
  float m = fmaxf(fmaxf(m0, m2), fmaxf(m4, m6));
#pragma unroll
  for (int off = 32; off; off >>= 1) m = fmaxf(m, __shfl_xor(m, off));
  float s = PEXPS(p0) + PEXPS(p1) + PEXPS(p2) + PEXPS(p3) +
            PEXPS(p4) + PEXPS(p5) + PEXPS(p6) + PEXPS(p7);
#pragma unroll
  for (int off = 32; off; off >>= 1) s += __shfl_xor(s, off);
  if (lane == 0) outPot[row] = logMarg[row] - (m + __logf(s));
}

// ---------------------------------------------------------------------------
// RT[d,i] = sum_j TF[d,j] * exp( GpT[j*S+i] + ut[i] + vt[j] )
// 512-thread version (8 waves/CU), 8x4 per thread — same occupancy fix as
// gemm_tn_k. Per-element accumulation order unchanged -> bit-identical RT.
// ---------------------------------------------------------------------------
__global__ __launch_bounds__(512) void rt_gemm_k(const float* __restrict__ TF,
                                                 const float* __restrict__ GpT,
                                                 const float* __restrict__ ut,
                                                 const float* __restrict__ vt,
                                                 float* __restrict__ RT) {
  __shared__ float As[16][128];  // As[kk][dd] = TF[(d0+dd)*S + k0+kk]
  __shared__ float Bs[16][128];  // Bs[kk][ii] = P^T[k0+kk, i0+ii]
  int t = threadIdx.x;
  int d0 = blockIdx.y * 128, i0 = blockIdx.x * 128;
  int tx = t & 31, ty = t >> 5;
  float acc[8][4];
#pragma unroll
  for (int r = 0; r < 8; ++r)
#pragma unroll
    for (int c = 0; c < 4; ++c) acc[r][c] = 0.f;

  int e = t * 4;
  int akk = e & 15, add0 = e >> 4;          // akk in {0,4,8,12}+, add0 0..127
  int bkk = e >> 7, bii = e & 127;          // bkk 0..15, bii 0..124
  float4 u4 = *(const float4*)&ut[i0 + bii];  // loop-invariant

  for (int k0 = 0; k0 < S; k0 += 16) {
    float4 av = *(const float4*)&TF[(d0 + add0) * S + k0 + akk];
    float4 g0 = *(const float4*)&GpT[(k0 + bkk) * S + i0 + bii];
    float v0 = vt[k0 + bkk];
    __syncthreads();
    As[akk + 0][add0] = av.x; As[akk + 1][add0] = av.y;
    As[akk + 2][add0] = av.z; As[akk + 3][add0] = av.w;
    float4 p0 = make_float4(__expf(g0.x + u4.x + v0), __expf(g0.y + u4.y + v0),
                            __expf(g0.z + u4.z + v0), __expf(g0.w + u4.w + v0));
    *(float4*)&Bs[bkk][bii] = p0;
    __syncthreads();
#pragma unroll
    for (int kk = 0; kk < 16; ++kk) {
      float a[8], b[4];
      *(float4*)&a[0] = *(const float4*)&As[kk][ty * 8];
      *(float4*)&a[4] = *(const float4*)&As[kk][ty * 8 + 4];
      *(float4*)&b[0] = *(const float4*)&Bs[kk][tx * 4];
#pragma unroll
      for (int r = 0; r < 8; ++r)
#pragma unroll
        for (int c = 0; c < 4; ++c) acc[r][c] = fmaf(a[r], b[c], acc[r][c]);
    }
  }
#pragma unroll
  for (int r = 0; r < 8; ++r) {
    int d = d0 + ty * 8 + r;
    *(float4*)&RT[d * S + i0 + tx * 4] = *(float4*)&acc[r][0];
  }
}

// dist2[i] += sum_{d in chunk} (qa[i]*QF[d,i] - RT[d,i])^2
__global__ __launch_bounds__(256) void dist2_partial_k(const float* __restrict__ QF,
                                                       const float* __restrict__ RT,
                                                       const float* __restrict__ qa,
                                                       float* __restrict__ dist2) {
  int ib = blockIdx.x & 7, dc = blockIdx.x >> 3;
  int i = ib * 256 + threadIdx.x;
  float qai = qa[i];
  float acc = 0.f;
  int d0 = dc * 256;
  for (int d = d0; d < d0 + 256; ++d) {
    float q = QF[d * S + i];
    float r = RT[d * S + i];
    float x = fmaf(qai, q, -r);
    acc = fmaf(x, x, acc);
  }
  atomicAdd(&dist2[i], acc);
}

__global__ __launch_bounds__(256) void loss_final_k(const float* __restrict__ dist2,
                                                    const float* __restrict__ label,
                                                    float* __restrict__ out) {
  int t = threadIdx.x;
  float acc = 0.f;
#pragma unroll
  for (int k = 0; k < 8; ++k) {
    int i = t + k * 256;
    float d2 = dist2[i];
    float dist = sqrtf(d2);
    float lab = label[i];
    float neg = fmaxf(MARGIN - dist, 0.f);
    acc += 0.5f * lab * d2 + 0.5f * (1.f - lab) * neg * neg;
  }
#pragma unroll
  for (int off = 32; off; off >>= 1) acc += __shfl_xor(acc, off);
  __shared__ float wsum[4];
  int wave = t >> 6, lane = t & 63;
  if (lane == 0) wsum[wave] = acc;
  __syncthreads();
  if (t == 0) out[0] = wsum[0] + wsum[1] + wsum[2] + wsum[3];
}

// ---------------------------------------------------------------------------
extern "C" void kernel_launch(void* const* d_in, const int* in_sizes, int n_in,
                              void* d_out, int out_size, void* d_ws, size_t ws_size,
                              hipStream_t stream) {
  const float* QF  = (const float*)d_in[0];  // [D, m] d-major
  const float* qa  = (const float*)d_in[1];  // [m]
  const float* TF  = (const float*)d_in[2];  // [D, n] d-major
  const float* ta  = (const float*)d_in[3];  // [n]
  const float* lab = (const float*)d_in[4];  // [m]
  float* out = (float*)d_out;

  float* ws = (float*)d_ws;
  float* Gp    = ws;                  // S*S : G' = -2 X^T Y  (reused as RT later)
  float* GpT   = Gp + S * S;          // S*S : G'^T
  float* ut    = GpT + S * S;         // S
  float* vt    = ut + S;              // S
  float* lmu   = vt + S;              // S
  float* lnu   = lmu + S;             // S
  float* dist2 = lnu + S;             // S
  // total: 2*S*S + 5*S floats ~= 33.6 MB

  init_marg_k<<<8, 256, 0, stream>>>(qa, ta, lmu, lnu, vt, dist2);
  colsumsq_k<<<64, 256, 0, stream>>>(TF, vt);  // vt = y2 (== v0 + y2)
  gemm_tn_k<<<dim3(16, 16), 512, 0, stream>>>(QF, TF, Gp, -2.0f);
  transpose_k<<<dim3(32, 32), 256, 0, stream>>>(Gp, GpT);

  for (int it = 0; it < ITERS; ++it) {
    lse8_k<<<512, 256, 0, stream>>>(Gp, vt, lmu, ut);   // row pass -> ut
    lse8_k<<<512, 256, 0, stream>>>(GpT, ut, lnu, vt);  // col pass -> vt
  }

  // RT = P @ tf computed transposed: RT[d,i]; aliases Gp (G' dead after loop)
  rt_gemm_k<<<dim3(16, 16), 512, 0, stream>>>(TF, GpT, ut, vt, Gp);
  dist2_partial_k<<<64, 256, 0, stream>>>(QF, Gp, qa, dist2);
  loss_final_k<<<1, 256, 0, stream>>>(dist2, lab, out);
}

// Round 11
// 4167.613 us; speedup vs baseline: 1.5814x; 1.0592x over previous
//
#include <hip/hip_runtime.h>
#include <math.h>

#define S 2048
#define MARGIN 0.7f
#define ITERS 500

// ---------------------------------------------------------------------------
// init: log-marginals, zero accumulators
// ---------------------------------------------------------------------------
__global__ __launch_bounds__(256) void init_marg_k(const float* __restrict__ qa,
                                                   const float* __restrict__ ta,
                                                   float* __restrict__ lmu,
                                                   float* __restrict__ lnu,
                                                   float* __restrict__ vt,
                                                   float* __restrict__ dist2) {
  int i = blockIdx.x * 256 + threadIdx.x;
  lmu[i] = __logf(qa[i]);
  lnu[i] = __logf(ta[i]);
  vt[i] = 0.f;     // will accumulate y2 (vt init = v0 + y2 = y2 since v0 = 0)
  dist2[i] = 0.f;
}

// vt[j] += sum_d TF[d,j]^2   (8 j-blocks x 8 d-chunks, atomic combine)
__global__ __launch_bounds__(256) void colsumsq_k(const float* __restrict__ TF,
                                                  float* __restrict__ vt) {
  int jb = blockIdx.x & 7, dc = blockIdx.x >> 3;
  int j = jb * 256 + threadIdx.x;
  int d0 = dc * 256;
  float acc = 0.f;
  for (int d = d0; d < d0 + 256; ++d) {
    float v = TF[d * S + j];
    acc = fmaf(v, v, acc);
  }
  atomicAdd(&vt[j], acc);
}

// ---------------------------------------------------------------------------
// C[i,j] = alpha * sum_k A[k*S+i] * B[k*S+j]
// 128x128 tile, BK=32 (half the barriers of BK=16), 512 threads, 8x4/thread.
// Per-element k-accumulation order unchanged (sequential 0..2047) ->
// bit-identical C vs all prior rounds.
// ---------------------------------------------------------------------------
__global__ __launch_bounds__(512) void gemm_tn_k(const float* __restrict__ A,
                                                 const float* __restrict__ B,
                                                 float* __restrict__ C, float alpha) {
  __shared__ float As[32][128];
  __shared__ float Bs[32][128];
  int t = threadIdx.x;
  int i0 = blockIdx.y * 128, j0 = blockIdx.x * 128;
  int tx = t & 31, ty = t >> 5;   // tx: 32 col-groups of 4, ty: 16 row-groups of 8
  float acc[8][4];
#pragma unroll
  for (int r = 0; r < 8; ++r)
#pragma unroll
    for (int c = 0; c < 4; ++c) acc[r][c] = 0.f;

  int e = t * 4;
  int dd0 = e >> 7, ii = e & 127;   // dd0 0..15
  int dd1 = dd0 + 16;
  for (int k0 = 0; k0 < S; k0 += 32) {
    float4 a0 = *(const float4*)&A[(k0 + dd0) * S + i0 + ii];
    float4 b0 = *(const float4*)&B[(k0 + dd0) * S + j0 + ii];
    float4 a1 = *(const float4*)&A[(k0 + dd1) * S + i0 + ii];
    float4 b1 = *(const float4*)&B[(k0 + dd1) * S + j0 + ii];
    __syncthreads();
    *(float4*)&As[dd0][ii] = a0; *(float4*)&Bs[dd0][ii] = b0;
    *(float4*)&As[dd1][ii] = a1; *(float4*)&Bs[dd1][ii] = b1;
    __syncthreads();
#pragma unroll
    for (int kk = 0; kk < 32; ++kk) {
      float a[8], b[4];
      *(float4*)&a[0] = *(const float4*)&As[kk][ty * 8];
      *(float4*)&a[4] = *(const float4*)&As[kk][ty * 8 + 4];
      *(float4*)&b[0] = *(const float4*)&Bs[kk][tx * 4];
#pragma unroll
      for (int r = 0; r < 8; ++r)
#pragma unroll
        for (int c = 0; c < 4; ++c) acc[r][c] = fmaf(a[r], b[c], acc[r][c]);
    }
  }
#pragma unroll
  for (int r = 0; r < 8; ++r) {
    int i = i0 + ty * 8 + r;
    float4 o = make_float4(acc[r][0] * alpha, acc[r][1] * alpha,
                           acc[r][2] * alpha, acc[r][3] * alpha);
    *(float4*)&C[i * S + j0 + tx * 4] = o;
  }
}

// ---------------------------------------------------------------------------
// out[j*S+i] = in[i*S+j]  (64x64 LDS tiles)
// ---------------------------------------------------------------------------
__global__ __launch_bounds__(256) void transpose_k(const float* __restrict__ in,
                                                   float* __restrict__ out) {
  __shared__ float tile[64][65];
  int i0 = blockIdx.y * 64, j0 = blockIdx.x * 64;
  int tx = threadIdx.x & 63, ty = threadIdx.x >> 6;  // ty 0..3
#pragma unroll
  for (int r = 0; r < 16; ++r) {
    int row = r * 4 + ty;
    tile[row][tx] = in[(i0 + row) * S + j0 + tx];
  }
  __syncthreads();
#pragma unroll
  for (int r = 0; r < 16; ++r) {
    int row = r * 4 + ty;
    out[(j0 + row) * S + i0 + tx] = tile[tx][row];
  }
}

// ---------------------------------------------------------------------------
// lse8_k: 256 blocks x 512 threads, WAVE-PER-ROW (8 rows/block), pot staged
// once per block. Same per-row reduction tree as all verified rounds ->
// bit-identical. Graph-serialized launches are the measured-best inter-pass
// barrier (~3.7us/pass; beats all 6 persistent sync mechanisms, R3-R9).
// ---------------------------------------------------------------------------
#define PADD(P, A) P.x += A.x; P.y += A.y; P.z += A.z; P.w += A.w
#define PMAX(P) fmaxf(fmaxf(P.x, P.y), fmaxf(P.z, P.w))
#define PEXPS(P) (__expf(P.x - m) + __expf(P.y - m) + __expf(P.z - m) + __expf(P.w - m))

__global__ __launch_bounds__(512) void lse8_k(const float* __restrict__ G,
                                              const float* __restrict__ inPot,
                                              const float* __restrict__ logMarg,
                                              float* __restrict__ outPot) {
  __shared__ float s_pot[S];
  const int t = threadIdx.x;
  const int wv = t >> 6, lane = t & 63;
  const int row = (int)blockIdx.x * 8 + wv;

  // stage pot: 512 threads x 4 floats = 8KB, coalesced, conflict-free
  {
    int e = t << 2;
    *(float4*)&s_pot[e] = *(const float4*)&inPot[e];
  }
  __syncthreads();

  const float* g = G + (size_t)row * S;
  const int j0 = lane << 2;
  float4 p0 = *(const float4*)&s_pot[j0];
  float4 p1 = *(const float4*)&s_pot[j0 + 256];
  float4 p2 = *(const float4*)&s_pot[j0 + 512];
  float4 p3 = *(const float4*)&s_pot[j0 + 768];
  float4 p4 = *(const float4*)&s_pot[j0 + 1024];
  float4 p5 = *(const float4*)&s_pot[j0 + 1280];
  float4 p6 = *(const float4*)&s_pot[j0 + 1536];
  float4 p7 = *(const float4*)&s_pot[j0 + 1792];
  float4 a0 = *(const float4*)&g[j0];
  float4 a1 = *(const float4*)&g[j0 + 256];
  float4 a2 = *(const float4*)&g[j0 + 512];
  float4 a3 = *(const float4*)&g[j0 + 768];
  float4 a4 = *(const float4*)&g[j0 + 1024];
  float4 a5 = *(const float4*)&g[j0 + 1280];
  float4 a6 = *(const float4*)&g[j0 + 1536];
  float4 a7 = *(const float4*)&g[j0 + 1792];
  PADD(p0, a0); PADD(p1, a1); PADD(p2, a2); PADD(p3, a3);
  PADD(p4, a4); PADD(p5, a5); PADD(p6, a6); PADD(p7, a7);
  float m0 = PMAX(p0), m1 = PMAX(p1), m2 = PMAX(p2), m3 = PMAX(p3);
  float m4 = PMAX(p4), m5 = PMAX(p5), m6 = PMAX(p6), m7 = PMAX(p7);
  m0 = fmaxf(m0, m1); m2 = fmaxf(m2, m3); m4 = fmaxf(m4, m5); m6 = fmaxf(m6, m7);
  float m = fmaxf(fmaxf(m0, m2), fmaxf(m4, m6));
#pragma unroll
  for (int off = 32; off; off >>= 1) m = fmaxf(m, __shfl_xor(m, off));
  float s = PEXPS(p0) + PEXPS(p1) + PEXPS(p2) + PEXPS(p3) +
            PEXPS(p4) + PEXPS(p5) + PEXPS(p6) + PEXPS(p7);
#pragma unroll
  for (int off = 32; off; off >>= 1) s += __shfl_xor(s, off);
  if (lane == 0) outPot[row] = logMarg[row] - (m + __logf(s));
}

// ---------------------------------------------------------------------------
// RT[d,i] = sum_j TF[d,j] * exp( GpT[j*S+i] + ut[i] + vt[j] )
// BK=32, 512 threads, 8x4/thread. As padded to [32][132]: the transposing
// scalar As-writes would be 8-way bank conflicts at stride 128; +4 pad makes
// them <=2-way (free) while keeping 16B alignment for the float4 reads.
// Per-element accumulation order unchanged -> bit-identical RT.
// ---------------------------------------------------------------------------
__global__ __launch_bounds__(512) void rt_gemm_k(const float* __restrict__ TF,
                                                 const float* __restrict__ GpT,
                                                 const float* __restrict__ ut,
                                                 const float* __restrict__ vt,
                                                 float* __restrict__ RT) {
  __shared__ float As[32][132];  // As[kk][dd] = TF[(d0+dd)*S + k0+kk]
  __shared__ float Bs[32][128];  // Bs[kk][ii] = P^T[k0+kk, i0+ii]
  int t = threadIdx.x;
  int d0 = blockIdx.y * 128, i0 = blockIdx.x * 128;
  int tx = t & 31, ty = t >> 5;
  float acc[8][4];
#pragma unroll
  for (int r = 0; r < 8; ++r)
#pragma unroll
    for (int c = 0; c < 4; ++c) acc[r][c] = 0.f;

  int e = t * 4;
  int akk = e & 31, add0 = e >> 5;          // akk {0,4,..,28}, add0 0..63
  int bkk0 = e >> 7, bii = e & 127;         // bkk0 0..15
  int bkk1 = bkk0 + 16;
  float4 u4 = *(const float4*)&ut[i0 + bii];  // loop-invariant

  for (int k0 = 0; k0 < S; k0 += 32) {
    float4 av0 = *(const float4*)&TF[(d0 + add0) * S + k0 + akk];
    float4 av1 = *(const float4*)&TF[(d0 + add0 + 64) * S + k0 + akk];
    float4 g0 = *(const float4*)&GpT[(k0 + bkk0) * S + i0 + bii];
    float4 g1 = *(const float4*)&GpT[(k0 + bkk1) * S + i0 + bii];
    float v0 = vt[k0 + bkk0], v1 = vt[k0 + bkk1];
    __syncthreads();
    As[akk + 0][add0] = av0.x; As[akk + 1][add0] = av0.y;
    As[akk + 2][add0] = av0.z; As[akk + 3][add0] = av0.w;
    As[akk + 0][add0 + 64] = av1.x; As[akk + 1][add0 + 64] = av1.y;
    As[akk + 2][add0 + 64] = av1.z; As[akk + 3][add0 + 64] = av1.w;
    float4 p0 = make_float4(__expf(g0.x + u4.x + v0), __expf(g0.y + u4.y + v0),
                            __expf(g0.z + u4.z + v0), __expf(g0.w + u4.w + v0));
    float4 p1 = make_float4(__expf(g1.x + u4.x + v1), __expf(g1.y + u4.y + v1),
                            __expf(g1.z + u4.z + v1), __expf(g1.w + u4.w + v1));
    *(float4*)&Bs[bkk0][bii] = p0;
    *(float4*)&Bs[bkk1][bii] = p1;
    __syncthreads();
#pragma unroll
    for (int kk = 0; kk < 32; ++kk) {
      float a[8], b[4];
      *(float4*)&a[0] = *(const float4*)&As[kk][ty * 8];
      *(float4*)&a[4] = *(const float4*)&As[kk][ty * 8 + 4];
      *(float4*)&b[0] = *(const float4*)&Bs[kk][tx * 4];
#pragma unroll
      for (int r = 0; r < 8; ++r)
#pragma unroll
        for (int c = 0; c < 4; ++c) acc[r][c] = fmaf(a[r], b[c], acc[r][c]);
    }
  }
#pragma unroll
  for (int r = 0; r < 8; ++r) {
    int d = d0 + ty * 8 + r;
    *(float4*)&RT[d * S + i0 + tx * 4] = *(float4*)&acc[r][0];
  }
}

// dist2[i] += sum_{d in chunk} (qa[i]*QF[d,i] - RT[d,i])^2
__global__ __launch_bounds__(256) void dist2_partial_k(const float* __restrict__ QF,
                                                       const float* __restrict__ RT,
                                                       const float* __restrict__ qa,
                                                       float* __restrict__ dist2) {
  int ib = blockIdx.x & 7, dc = blockIdx.x >> 3;
  int i = ib * 256 + threadIdx.x;
  float qai = qa[i];
  float acc = 0.f;
  int d0 = dc * 256;
  for (int d = d0; d < d0 + 256; ++d) {
    float q = QF[d * S + i];
    float r = RT[d * S + i];
    float x = fmaf(qai, q, -r);
    acc = fmaf(x, x, acc);
  }
  atomicAdd(&dist2[i], acc);
}

__global__ __launch_bounds__(256) void loss_final_k(const float* __restrict__ dist2,
                                                    const float* __restrict__ label,
                                                    float* __restrict__ out) {
  int t = threadIdx.x;
  float acc = 0.f;
#pragma unroll
  for (int k = 0; k < 8; ++k) {
    int i = t + k * 256;
    float d2 = dist2[i];
    float dist = sqrtf(d2);
    float lab = label[i];
    float neg = fmaxf(MARGIN - dist, 0.f);
    acc += 0.5f * lab * d2 + 0.5f * (1.f - lab) * neg * neg;
  }
#pragma unroll
  for (int off = 32; off; off >>= 1) acc += __shfl_xor(acc, off);
  __shared__ float wsum[4];
  int wave = t >> 6, lane = t & 63;
  if (lane == 0) wsum[wave] = acc;
  __syncthreads();
  if (t == 0) out[0] = wsum[0] + wsum[1] + wsum[2] + wsum[3];
}

// ---------------------------------------------------------------------------
extern "C" void kernel_launch(void* const* d_in, const int* in_sizes, int n_in,
                              void* d_out, int out_size, void* d_ws, size_t ws_size,
                              hipStream_t stream) {
  const float* QF  = (const float*)d_in[0];  // [D, m] d-major
  const float* qa  = (const float*)d_in[1];  // [m]
  const float* TF  = (const float*)d_in[2];  // [D, n] d-major
  const float* ta  = (const float*)d_in[3];  // [n]
  const float* lab = (const float*)d_in[4];  // [m]
  float* out = (float*)d_out;

  float* ws = (float*)d_ws;
  float* Gp    = ws;                  // S*S : G' = -2 X^T Y  (reused as RT later)
  float* GpT   = Gp + S * S;          // S*S : G'^T
  float* ut    = GpT + S * S;         // S
  float* vt    = ut + S;              // S
  float* lmu   = vt + S;              // S
  float* lnu   = lmu + S;             // S
  float* dist2 = lnu + S;             // S
  // total: 2*S*S + 5*S floats ~= 33.6 MB

  init_marg_k<<<8, 256, 0, stream>>>(qa, ta, lmu, lnu, vt, dist2);
  colsumsq_k<<<64, 256, 0, stream>>>(TF, vt);  // vt = y2 (== v0 + y2)
  gemm_tn_k<<<dim3(16, 16), 512, 0, stream>>>(QF, TF, Gp, -2.0f);
  transpose_k<<<dim3(32, 32), 256, 0, stream>>>(Gp, GpT);

  for (int it = 0; it < ITERS; ++it) {
    lse8_k<<<256, 512, 0, stream>>>(Gp, vt, lmu, ut);   // row pass -> ut
    lse8_k<<<256, 512, 0, stream>>>(GpT, ut, lnu, vt);  // col pass -> vt
  }

  // RT = P @ tf computed transposed: RT[d,i]; aliases Gp (G' dead after loop)
  rt_gemm_k<<<dim3(16, 16), 512, 0, stream>>>(TF, GpT, ut, vt, Gp);
  dist2_partial_k<<<64, 256, 0, stream>>>(QF, Gp, qa, dist2);
  loss_final_k<<<1, 256, 0, stream>>>(dist2, lab, out);
}